// Round 8
// baseline (217.043 us; speedup 1.0000x reference)
//
#include <hip/hip_runtime.h>

#define BS 16
#define NH 16
#define LQ 4096
#define DH 32

constexpr int SPLIT = 8;
constexpr int SCHUNK = LQ / SPLIT;          // 512 s per block; 128 s per wave; 4 stages x 32 s
constexpr size_t OUT_ELEMS = (size_t)BS * NH * LQ * DH;   // 33,554,432
constexpr int HDE = NH * DH * DH;           // 16384

__device__ __forceinline__ void fma4(float4& a, float s, const float4& v) {
    a.x = fmaf(s, v.x, a.x);
    a.y = fmaf(s, v.y, a.y);
    a.z = fmaf(s, v.z, a.z);
    a.w = fmaf(s, v.w, a.w);
}

// ---------------- Kernel A: partial K@V over an s-chunk ----------------
// 2048 blocks x 256 thr. ZERO barriers in the main loop: fully wave-private
// pipeline using only R2-proven primitives (global->reg loads, ds_write from
// regs, compiler-managed waitcnts, wave-private lgkmcnt(0); counted-vmcnt and
// cross-wave raw barriers are abandoned after 3 correctness failures, per
// m152). Wave owns 128 s in 4 stages of 32 s; one rotating reg set (16 float4)
// holds the in-flight stage; t-loop NOT unrolled so the compiler cannot hoist
// all stages' loads (R2's 128-VGPR serialization bug). Loads for stage t+1
// issue before compute of stage t (~1024 cyc VALU) -> HBM latency hidden
// in-wave; rest by TLP (32 KB LDS + ~80 VGPR -> 4 blocks/CU = 16 waves).
// K stored [d][sg ^ (d>>2)] via write-side XOR (reg->ds_write, so swizzle is
// free), V linear [s][e]: both read conflict-free (R2/R7 measured 0).
__global__ __launch_bounds__(256, 4) void kv_partial(const float* __restrict__ k,
                                                     const float* __restrict__ v,
                                                     float* __restrict__ part) {
    __shared__ float lds[8192];             // wave w owns [w*2048, (w+1)*2048): K 1024 | V 1024
    const int tid  = threadIdx.x;
    const int wid  = tid >> 6;
    const int lane = tid & 63;
    const int p    = blockIdx.x & (SPLIT - 1);
    const int bh   = blockIdx.x >> 3;

    const int dgl = lane >> 3;              // 0..7
    const int d0  = dgl << 2;
    const int e0  = (lane & 7) << 2;

    const float* kb = k + (size_t)bh * DH * LQ;
    const float* vb = v + (size_t)bh * LQ * DH;
    const int s_wave = p * SCHUNK + (wid << 7);    // this wave's 128-s base

    float* kw = lds + (wid << 11);
    float* vw = kw + 1024;

    // global addressing: lane covers K row kd = lane>>1, s-half sh = (lane&1)*16
    const int kd = lane >> 1;
    const float* kg = kb + (size_t)kd * LQ + s_wave + ((lane & 1) << 4);
    const float* vg = vb + ((size_t)s_wave << 5) + (lane << 2);

    // K LDS store: row kd, s-group sg = (lane&1)*4 + j at slot sg ^ (kd>>2)
    int kst[4];
#pragma unroll
    for (int j = 0; j < 4; ++j)
        kst[j] = (kd << 5) + ((((((lane & 1) << 2) | j) ^ (kd >> 2)) & 7) << 2);

    float4 kr[4], vr[4];
#pragma unroll
    for (int j = 0; j < 4; ++j) kr[j] = *(const float4*)(kg + (j << 2));
#pragma unroll
    for (int i = 0; i < 4; ++i) vr[i] = *(const float4*)(vg + (i << 8));

    float4 acc0 = {0,0,0,0}, acc1 = {0,0,0,0}, acc2 = {0,0,0,0}, acc3 = {0,0,0,0};

#pragma unroll 1
    for (int t = 0; t < 4; ++t) {
        // wave-private WAR guard: prior stage's ds_reads all returned (their
        // data already fed FMAs, so this is ~free); then overwrite the buffer.
        asm volatile("s_waitcnt lgkmcnt(0)" ::: "memory");
#pragma unroll
        for (int j = 0; j < 4; ++j) *(float4*)(kw + kst[j]) = kr[j];
#pragma unroll
        for (int i = 0; i < 4; ++i) *(float4*)(vw + (i << 8) + (lane << 2)) = vr[i];

        // issue next stage's global loads NOW (overwrite regs after ds_write
        // consumed them; in-order issue makes this safe); they fly during the
        // whole compute phase below.
        if (t < 3) {
            const int so = (t + 1) << 5;
#pragma unroll
            for (int j = 0; j < 4; ++j) kr[j] = *(const float4*)(kg + so + (j << 2));
#pragma unroll
            for (int i = 0; i < 4; ++i) vr[i] = *(const float4*)(vg + ((size_t)so << 5) + (i << 8));
        }

        // compute stage t from this wave's LDS (compiler inserts lgkmcnt for
        // the ds_write->ds_read dependency; per-wave LDS ops are in-order).
#pragma unroll
        for (int g = 0; g < 8; ++g) {
            const int ko = (d0 << 5) + ((g ^ dgl) << 2);
            const float4 kq0 = *(const float4*)(kw + ko);
            const float4 kq1 = *(const float4*)(kw + ko + 32);
            const float4 kq2 = *(const float4*)(kw + ko + 64);
            const float4 kq3 = *(const float4*)(kw + ko + 96);
            const int vo = (g << 7) + e0;
            const float4 vv0 = *(const float4*)(vw + vo);
            const float4 vv1 = *(const float4*)(vw + vo + 32);
            const float4 vv2 = *(const float4*)(vw + vo + 64);
            const float4 vv3 = *(const float4*)(vw + vo + 96);

            fma4(acc0, kq0.x, vv0); fma4(acc0, kq0.y, vv1); fma4(acc0, kq0.z, vv2); fma4(acc0, kq0.w, vv3);
            fma4(acc1, kq1.x, vv0); fma4(acc1, kq1.y, vv1); fma4(acc1, kq1.z, vv2); fma4(acc1, kq1.w, vv3);
            fma4(acc2, kq2.x, vv0); fma4(acc2, kq2.y, vv1); fma4(acc2, kq2.z, vv2); fma4(acc2, kq2.w, vv3);
            fma4(acc3, kq3.x, vv0); fma4(acc3, kq3.y, vv1); fma4(acc3, kq3.z, vv2); fma4(acc3, kq3.w, vv3);
        }
    }

    // wave partial -> its OWN region (first 1024 floats), then one barrier,
    // then cross-wave sum. No other wave ever reads my region before the
    // barrier; my own reads are done (lgkmcnt guard).
    asm volatile("s_waitcnt lgkmcnt(0)" ::: "memory");
    *(float4*)(kw + ((d0 + 0) << 5) + e0) = acc0;
    *(float4*)(kw + ((d0 + 1) << 5) + e0) = acc1;
    *(float4*)(kw + ((d0 + 2) << 5) + e0) = acc2;
    *(float4*)(kw + ((d0 + 3) << 5) + e0) = acc3;
    __syncthreads();

    const int t4 = tid << 2;
    const float4 r0 = *(const float4*)(lds + t4);
    const float4 r1 = *(const float4*)(lds + 2048 + t4);
    const float4 r2 = *(const float4*)(lds + 4096 + t4);
    const float4 r3 = *(const float4*)(lds + 6144 + t4);
    float4 r;
    r.x = (r0.x + r1.x) + (r2.x + r3.x);
    r.y = (r0.y + r1.y) + (r2.y + r3.y);
    r.z = (r0.z + r1.z) + (r2.z + r3.z);
    r.w = (r0.w + r1.w) + (r2.w + r3.w);
    *(float4*)(part + ((size_t)p * (BS * NH) + bh) * 1024 + t4) = r;
}

// ---------------- Kernel B: reduce partials + softmax over batch axis ----------------
__global__ __launch_bounds__(256) void softmax_b(const float* __restrict__ part,
                                                 float* __restrict__ wts) {
    int idx = blockIdx.x * 256 + threadIdx.x;     // 0..16383 = h*1024 + d*32 + e

    float sc[BS];
#pragma unroll
    for (int b = 0; b < BS; ++b) {
        float s = 0.f;
#pragma unroll
        for (int pp = 0; pp < SPLIT; ++pp) {
            s += part[(((size_t)pp * BS * NH + (size_t)b * NH) << 10) + idx];
        }
        sc[b] = s * (1.0f / 64.0f);               // / sqrt(4096)
    }

    float m = sc[0];
#pragma unroll
    for (int b = 1; b < BS; ++b) m = fmaxf(m, sc[b]);
    float sum = 0.f;
#pragma unroll
    for (int b = 0; b < BS; ++b) { sc[b] = __expf(sc[b] - m); sum += sc[b]; }
    float inv = 1.0f / sum;
#pragma unroll
    for (int b = 0; b < BS; ++b) {
        wts[(size_t)b * HDE + idx] = sc[b] * inv;
    }
}

// ---------------- Kernel C: out = Q @ W ----------------
// 8192 blocks x 256 thr. Q tile staged in LDS (stride 36 -> conflict-free b128 reads),
// W column-block in 128 VGPRs. 1 ds_read_b128 per 16 FMA.
__global__ __launch_bounds__(256, 2) void qw(const float* __restrict__ q,
                                             const float* __restrict__ wts,
                                             float* __restrict__ out) {
    __shared__ float qs[128 * 36];
    const int blk = blockIdx.x;
    const int bh  = blk >> 5;
    const int lt  = blk & 31;
    const int tid = threadIdx.x;

    const float* qbase = q + ((size_t)bh * LQ + lt * 128) * DH;

#pragma unroll
    for (int pp = 0; pp < 4; ++pp) {
        const int idx = pp * 256 + tid;           // float4 index 0..1023
        const int row = idx >> 3;
        const int c4  = idx & 7;
        const float4 t = *(const float4*)(qbase + idx * 4);
        *(float4*)(qs + row * 36 + c4 * 4) = t;
    }

    const int lsub = tid >> 3;                    // 0..31
    const int e0   = (tid & 7) << 2;

    float4 Wf[32];
    const float* wbase = wts + (size_t)bh * (DH * DH) + e0;
#pragma unroll
    for (int d = 0; d < 32; ++d) Wf[d] = *(const float4*)(wbase + d * DH);

    __syncthreads();

    float* obase = out + ((size_t)bh * LQ + lt * 128) * DH;

#pragma unroll
    for (int r = 0; r < 4; ++r) {
        const int lr = lsub + r * 32;
        const float* qrow = qs + lr * 36;
        float4 acc = {0,0,0,0};
#pragma unroll
        for (int d4 = 0; d4 < 32; d4 += 4) {
            const float4 qv = *(const float4*)(qrow + d4);
            fma4(acc, qv.x, Wf[d4 + 0]);
            fma4(acc, qv.y, Wf[d4 + 1]);
            fma4(acc, qv.z, Wf[d4 + 2]);
            fma4(acc, qv.w, Wf[d4 + 3]);
        }
        *(float4*)(obase + (size_t)lr * DH + e0) = acc;
    }
}

extern "C" void kernel_launch(void* const* d_in, const int* in_sizes, int n_in,
                              void* d_out, int out_size, void* d_ws, size_t ws_size,
                              hipStream_t stream) {
    const float* q = (const float*)d_in[0];
    const float* k = (const float*)d_in[1];
    const float* v = (const float*)d_in[2];
    float* out  = (float*)d_out;
    float* wts  = out + OUT_ELEMS;          // attn_weights region of d_out
    float* part = (float*)d_ws;             // 8 MB of partials

    kv_partial<<<BS * NH * SPLIT, 256, 0, stream>>>(k, v, part);
    softmax_b<<<HDE / 256, 256, 0, stream>>>(part, wts);
    qw<<<BS * NH * (LQ / 128), 256, 0, stream>>>(q, wts, out);
}

// Round 9
// 145.962 us; speedup vs baseline: 1.4870x; 1.4870x over previous
//
#include <hip/hip_runtime.h>

#define BS 16
#define NH 16
#define LQ 4096
#define DH 32

constexpr size_t OUT_ELEMS = (size_t)BS * NH * LQ * DH;   // 33,554,432
constexpr int HDE = NH * DH * DH;           // 16384

// global -> LDS direct copy, 16 B per lane. dst is the WAVE-UNIFORM base;
// HW writes dst + lane*16. src is per-lane.
__device__ __forceinline__ void async_cp16(float* dst, const float* src) {
    __builtin_amdgcn_global_load_lds(
        (const __attribute__((address_space(1))) void*)src,
        (__attribute__((address_space(3))) void*)dst, 16, 0, 0);
}

__device__ __forceinline__ void fma4(float4& a, float s, const float4& v) {
    a.x = fmaf(s, v.x, a.x);
    a.y = fmaf(s, v.y, a.y);
    a.z = fmaf(s, v.z, a.z);
    a.w = fmaf(s, v.w, a.w);
}

// ---------------- Kernel A: partial K@V, ONE-SHOT blocks ----------------
// Kernel-C-style structure (the only one that has hit ~86% of HBM floor this
// session): per 128-s window: 8 glls/wave fill 32 KB -> ONE __syncthreads ->
// one long compute phase. No counted vmcnt, no raw barriers, no ds_write
// staging (R8: ds_write K-rows = 4-way bank conflict + reg-set spills).
// Overlap comes from block turnover at 5 blocks/CU, exactly like kernel C.
// K staged [32 d][128 s] with XOR swizzle slot_g = (g&24)|((g^((d>>2)&7))&7)
// applied on the gll SOURCE address (dest linear) -> ds_read_b128 of rows
// d0..d0+3 at wave-uniform g: 8 dgl-groups hit 8 distinct bank-quads,
// broadcast within -> conflict-free. V linear [128 s][32 e] (proven 0-confl).
// NCH windows per block (accumulated in regs): NCH=1 if ws fits 33.5 MB of
// partials (8192 blocks), else NCH=4 (2048 blocks, 8 MB).
template<int NCH>
__global__ __launch_bounds__(256, 5) void kv_partial(const float* __restrict__ k,
                                                     const float* __restrict__ v,
                                                     float* __restrict__ part) {
    __shared__ float lds[8192];             // K[32][128] swz | V[128][32] linear
    const int tid  = threadIdx.x;
    const int wid  = tid >> 6;
    const int lane = tid & 63;
    const int nsplit = 32 / NCH;
    const int p  = blockIdx.x % nsplit;
    const int bh = blockIdx.x / nsplit;

    const int dgl = lane >> 3;              // 0..7
    const int d0  = dgl << 2;
    const int e0  = (lane & 7) << 2;

    const float* kb = k + (size_t)bh * DH * LQ;
    const float* vb = v + (size_t)bh * LQ * DH;
    float* kt = lds;                        // 4096 floats
    float* vt = lds + 4096;                 // 4096 floats

    // per-gll constants. K gll j covers rows {2j, 2j+1}: lanes 0-31 -> row 2j,
    // lanes 32-63 -> row 2j+1; stored slot gs = lane&31 holds source s-group
    // gsrc = (gs&24) | ((gs ^ ((d>>2)&7))&7)  (involution with the read XOR).
    size_t ksrc[4];
    int kdst[4];
    size_t vsrc[4];
#pragma unroll
    for (int i = 0; i < 4; ++i) {
        const int j = (wid << 2) + i;
        const int d = (j << 1) + (lane >> 5);
        const int gs = lane & 31;
        const int gsrc = (gs & 24) | ((gs ^ ((j >> 1) & 7)) & 7);
        ksrc[i] = (size_t)d * LQ + (gsrc << 2);
        kdst[i] = j << 8;                   // 2 rows = 256 floats
        vsrc[i] = (size_t)(j << 8) + (lane << 2);   // contiguous 1 KB
    }

    float4 acc0 = {0,0,0,0}, acc1 = {0,0,0,0}, acc2 = {0,0,0,0}, acc3 = {0,0,0,0};

#pragma unroll
    for (int c = 0; c < NCH; ++c) {
        const int s0 = (p * NCH + c) << 7;  // window's 128-s base
#pragma unroll
        for (int i = 0; i < 4; ++i) async_cp16(kt + kdst[i], kb + ksrc[i] + s0);
#pragma unroll
        for (int i = 0; i < 4; ++i) async_cp16(vt + kdst[i], vb + ((size_t)s0 << 5) + vsrc[i]);
        __syncthreads();                    // drains vmcnt(0): tiles resident

        // wave w covers s-groups [8w, 8w+8) of this window
#pragma unroll
        for (int gg = 0; gg < 8; ++gg) {
            const int g  = (wid << 3) + gg;
            const int ko = ((g & 24) | ((g ^ dgl) & 7)) << 2;
            const float4 kq0 = *(const float4*)(kt + ((d0 + 0) << 7) + ko);
            const float4 kq1 = *(const float4*)(kt + ((d0 + 1) << 7) + ko);
            const float4 kq2 = *(const float4*)(kt + ((d0 + 2) << 7) + ko);
            const float4 kq3 = *(const float4*)(kt + ((d0 + 3) << 7) + ko);
            const int vo = (g << 7) + e0;
            const float4 vv0 = *(const float4*)(vt + vo);
            const float4 vv1 = *(const float4*)(vt + vo + 32);
            const float4 vv2 = *(const float4*)(vt + vo + 64);
            const float4 vv3 = *(const float4*)(vt + vo + 96);

            fma4(acc0, kq0.x, vv0); fma4(acc0, kq0.y, vv1); fma4(acc0, kq0.z, vv2); fma4(acc0, kq0.w, vv3);
            fma4(acc1, kq1.x, vv0); fma4(acc1, kq1.y, vv1); fma4(acc1, kq1.z, vv2); fma4(acc1, kq1.w, vv3);
            fma4(acc2, kq2.x, vv0); fma4(acc2, kq2.y, vv1); fma4(acc2, kq2.z, vv2); fma4(acc2, kq2.w, vv3);
            fma4(acc3, kq3.x, vv0); fma4(acc3, kq3.y, vv1); fma4(acc3, kq3.z, vv2); fma4(acc3, kq3.w, vv3);
        }
        __syncthreads();                    // all reads done before next fill / reduce
    }

    // cross-wave reduce: wave w -> lds[w*1024 + d*32 + e] (aliases kt; ordered
    // by the final __syncthreads above)
    *(float4*)(lds + (wid << 10) + ((d0 + 0) << 5) + e0) = acc0;
    *(float4*)(lds + (wid << 10) + ((d0 + 1) << 5) + e0) = acc1;
    *(float4*)(lds + (wid << 10) + ((d0 + 2) << 5) + e0) = acc2;
    *(float4*)(lds + (wid << 10) + ((d0 + 3) << 5) + e0) = acc3;
    __syncthreads();

    const int t4 = tid << 2;
    const float4 r0 = *(const float4*)(lds + t4);
    const float4 r1 = *(const float4*)(lds + 1024 + t4);
    const float4 r2 = *(const float4*)(lds + 2048 + t4);
    const float4 r3 = *(const float4*)(lds + 3072 + t4);
    float4 r;
    r.x = (r0.x + r1.x) + (r2.x + r3.x);
    r.y = (r0.y + r1.y) + (r2.y + r3.y);
    r.z = (r0.z + r1.z) + (r2.z + r3.z);
    r.w = (r0.w + r1.w) + (r2.w + r3.w);
    *(float4*)(part + ((size_t)p * (BS * NH) + bh) * 1024 + t4) = r;
}

// ---------------- Kernel B1: reduce partials over p (fully parallel) ----------------
// grid 1024 blocks: thread (b, idx) sums nsp partials, coalesced. scores live
// in the wts output region (overwritten in-place by B2).
__global__ __launch_bounds__(256) void reduce_p(const float* __restrict__ part,
                                                float* __restrict__ scores, int nsp) {
    const int gidx = blockIdx.x * 256 + threadIdx.x;   // b*16384 + idx
    const int b    = gidx >> 14;
    const int idx  = gidx & 16383;
    float s = 0.f;
    for (int pp = 0; pp < nsp; ++pp)
        s += part[((size_t)pp << 18) + ((size_t)b << 14) + idx];
    scores[gidx] = s * (1.0f / 64.0f);                 // / sqrt(4096)
}

// ---------------- Kernel B2: softmax over batch axis (in-place on scores) ----------------
__global__ __launch_bounds__(256) void softmax_b(float* __restrict__ wts) {
    const int idx = blockIdx.x * 256 + threadIdx.x;    // 0..16383 = h*1024+d*32+e

    float sc[BS];
#pragma unroll
    for (int b = 0; b < BS; ++b) sc[b] = wts[((size_t)b << 14) + idx];
    float m = sc[0];
#pragma unroll
    for (int b = 1; b < BS; ++b) m = fmaxf(m, sc[b]);
    float sum = 0.f;
#pragma unroll
    for (int b = 0; b < BS; ++b) { sc[b] = __expf(sc[b] - m); sum += sc[b]; }
    float inv = 1.0f / sum;
#pragma unroll
    for (int b = 0; b < BS; ++b) wts[((size_t)b << 14) + idx] = sc[b] * inv;
}

// ---------------- Kernel C: out = Q @ W ----------------
// 8192 blocks x 256 thr. Q tile staged in LDS (stride 36 -> conflict-free b128 reads),
// W column-block in 128 VGPRs. 1 ds_read_b128 per 16 FMA.
__global__ __launch_bounds__(256, 2) void qw(const float* __restrict__ q,
                                             const float* __restrict__ wts,
                                             float* __restrict__ out) {
    __shared__ float qs[128 * 36];
    const int blk = blockIdx.x;
    const int bh  = blk >> 5;
    const int lt  = blk & 31;
    const int tid = threadIdx.x;

    const float* qbase = q + ((size_t)bh * LQ + lt * 128) * DH;

#pragma unroll
    for (int pp = 0; pp < 4; ++pp) {
        const int idx = pp * 256 + tid;           // float4 index 0..1023
        const int row = idx >> 3;
        const int c4  = idx & 7;
        const float4 t = *(const float4*)(qbase + idx * 4);
        *(float4*)(qs + row * 36 + c4 * 4) = t;
    }

    const int lsub = tid >> 3;                    // 0..31
    const int e0   = (tid & 7) << 2;

    // W for this bh in [b][h][d][e] layout: wts[(b*16+h)*1024 ...] with
    // bh = b*16+h -> base = bh*1024? NO: wts is [b][h*1024+d*32+e] = b*16384 + h*1024.
    const int b = bh >> 4, h = bh & 15;
    float4 Wf[32];
    const float* wbase = wts + ((size_t)b << 14) + ((size_t)h << 10) + e0;
#pragma unroll
    for (int d = 0; d < 32; ++d) Wf[d] = *(const float4*)(wbase + d * DH);

    __syncthreads();

    float* obase = out + ((size_t)bh * LQ + lt * 128) * DH;

#pragma unroll
    for (int r = 0; r < 4; ++r) {
        const int lr = lsub + r * 32;
        const float* qrow = qs + lr * 36;
        float4 acc = {0,0,0,0};
#pragma unroll
        for (int d4 = 0; d4 < 32; d4 += 4) {
            const float4 qv = *(const float4*)(qrow + d4);
            fma4(acc, qv.x, Wf[d4 + 0]);
            fma4(acc, qv.y, Wf[d4 + 1]);
            fma4(acc, qv.z, Wf[d4 + 2]);
            fma4(acc, qv.w, Wf[d4 + 3]);
        }
        *(float4*)(obase + (size_t)lr * DH + e0) = acc;
    }
}

extern "C" void kernel_launch(void* const* d_in, const int* in_sizes, int n_in,
                              void* d_out, int out_size, void* d_ws, size_t ws_size,
                              hipStream_t stream) {
    const float* q = (const float*)d_in[0];
    const float* k = (const float*)d_in[1];
    const float* v = (const float*)d_in[2];
    float* out  = (float*)d_out;
    float* wts  = out + OUT_ELEMS;          // attn_weights region of d_out
    float* part = (float*)d_ws;

    const size_t need32 = (size_t)32 * 256 * 1024 * 4;   // 33.55 MB of partials
    int nsp;
    if (ws_size >= need32) {
        kv_partial<1><<<256 * 32, 256, 0, stream>>>(k, v, part);
        nsp = 32;
    } else {
        kv_partial<4><<<256 * 8, 256, 0, stream>>>(k, v, part);
        nsp = 8;
    }
    reduce_p<<<(BS * HDE) / 256, 256, 0, stream>>>(part, wts, nsp);  // scores -> wts region
    softmax_b<<<HDE / 256, 256, 0, stream>>>(wts);                   // in-place softmax
    qw<<<BS * NH * (LQ / 128), 256, 0, stream>>>(q, wts, out);
}